// Round 1
// baseline (8404.235 us; speedup 1.0000x reference)
//
#include <hip/hip_runtime.h>
#include <cstdint>

// ODEModel: y0 = mean_T(x0[B,200,6]); 101 RK4 steps of 6->50->50->6 ReLU MLP.
// One thread per batch element.
//
// R2 redesign: the R0->R1 evidence (4x "VALU bloat" fix moved runtime only 5%)
// says the kernel is weight-load LATENCY bound, not VALU-issue bound: 1 wave/SIMD
// (grid == 256 blocks == 1 block/CU) gives zero TLP, and the scalar-load path's
// prefetch depth is capped by the ~102-SGPR file (~110 stall cycles per s_load
// chunk => 22k stall cycles per eval vs 6.4k FMA cycles).
// Fix: stage all weights in LDS once (padded to float4 rows), read them as
// wave-uniform broadcast ds_read_b128, and let the compiler pipeline with a big
// VGPR budget (__launch_bounds__(256,1): grid caps occupancy at 1 wave/SIMD
// anyway, so up to ~450 VGPRs are free).
// Layer-2 stays a rolled loop (dynamic i) to keep the RK4 body ~10KB (I$-safe);
// h1 is echoed through LDS [j][tid] (lane==bank, conflict-free) because VGPR
// arrays cannot be runtime-indexed.
// Numerics: identical op order to R1 (b-init, ascending i, fmaf, same relu
// placement); pads multiply by exact 0.0f -> absmax unchanged.

#define D_IN   6
#define H      50
#define HP     52      // W1/W2 row stride in floats -> 13 float4, 16B-aligned
#define W3P    8       // W3 row stride -> 2 float4
#define T_LEN  200
#define NTHR   256

// LDS layout in floats (all offsets multiples of 4 -> float4-aligned)
#define OFF_W1 0                   // [6][52]  = 312
#define OFF_B1 (OFF_W1 + D_IN*HP)  // 312, len 52
#define OFF_W2 (OFF_B1 + HP)       // 364, [50][52] = 2600
#define OFF_B2 (OFF_W2 + H*HP)     // 2964, len 52
#define OFF_W3 (OFF_B2 + HP)       // 3016, [50][8] = 400
#define OFF_B3 (OFF_W3 + H*W3P)    // 3416, len 8
#define OFF_TS (OFF_B3 + W3P)      // 3424, len 104
#define OFF_H1 (OFF_TS + 104)      // 3528, [50][256] = 12800
#define SMEM_FLOATS (OFF_H1 + H*NTHR)   // 16328 floats = 65312 B (< 64KiB)

__device__ __forceinline__ void mlp_eval(
    const float* __restrict__ sm, int tid, const float yt[D_IN], float k[D_IN])
{
    // ---- layer 1: 6 -> 50 (static unroll; 300 FMA) ----
    float h1[HP];
    {
        const float4* B1 = (const float4*)(sm + OFF_B1);
#pragma unroll
        for (int q = 0; q < HP / 4; ++q) {
            float4 v = B1[q];
            h1[4 * q + 0] = v.x; h1[4 * q + 1] = v.y;
            h1[4 * q + 2] = v.z; h1[4 * q + 3] = v.w;
        }
#pragma unroll
        for (int i = 0; i < D_IN; ++i) {
            float v = yt[i];
            const float4* Wr = (const float4*)(sm + OFF_W1 + i * HP);
#pragma unroll
            for (int q = 0; q < HP / 4; ++q) {
                float4 w = Wr[q];
                h1[4 * q + 0] = fmaf(v, w.x, h1[4 * q + 0]);
                h1[4 * q + 1] = fmaf(v, w.y, h1[4 * q + 1]);
                h1[4 * q + 2] = fmaf(v, w.z, h1[4 * q + 2]);
                h1[4 * q + 3] = fmaf(v, w.w, h1[4 * q + 3]);
            }
        }
    }

    // echo relu(h1) through LDS so layer 2 can index it dynamically.
    // layout [j][tid]: lane l -> bank (l % 32), 2 lanes/bank == free.
    float* e = (float*)(sm + OFF_H1) + tid;
#pragma unroll
    for (int j = 0; j < H; ++j) e[j * NTHR] = fmaxf(h1[j], 0.0f);

    // ---- layer 2: 50 -> 50 (rolled over i; 2500 FMA) ----
    float h2[HP];
    {
        const float4* B2 = (const float4*)(sm + OFF_B2);
#pragma unroll
        for (int q = 0; q < HP / 4; ++q) {
            float4 v = B2[q];
            h2[4 * q + 0] = v.x; h2[4 * q + 1] = v.y;
            h2[4 * q + 2] = v.z; h2[4 * q + 3] = v.w;
        }
    }
#pragma unroll 2
    for (int i = 0; i < H; ++i) {
        float v = sm[OFF_H1 + i * NTHR + tid];               // relu'd h1[i]
        const float4* Wr = (const float4*)(sm + OFF_W2 + i * HP);
#pragma unroll
        for (int q = 0; q < HP / 4; ++q) {
            float4 w = Wr[q];
            h2[4 * q + 0] = fmaf(v, w.x, h2[4 * q + 0]);
            h2[4 * q + 1] = fmaf(v, w.y, h2[4 * q + 1]);
            h2[4 * q + 2] = fmaf(v, w.z, h2[4 * q + 2]);
            h2[4 * q + 3] = fmaf(v, w.w, h2[4 * q + 3]);
        }
    }

    // ---- layer 3: 50 -> 6 (static unroll; relu at consumption; 300 FMA) ----
    {
        const float4* B3 = (const float4*)(sm + OFF_B3);
        float4 b30 = B3[0], b31 = B3[1];
        k[0] = b30.x; k[1] = b30.y; k[2] = b30.z;
        k[3] = b30.w; k[4] = b31.x; k[5] = b31.y;
    }
#pragma unroll
    for (int i = 0; i < H; ++i) {
        float v = fmaxf(h2[i], 0.0f);
        const float4* Wr = (const float4*)(sm + OFF_W3 + i * W3P);
        float4 w0 = Wr[0], w1 = Wr[1];
        k[0] = fmaf(v, w0.x, k[0]);
        k[1] = fmaf(v, w0.y, k[1]);
        k[2] = fmaf(v, w0.z, k[2]);
        k[3] = fmaf(v, w0.w, k[3]);
        k[4] = fmaf(v, w1.x, k[4]);
        k[5] = fmaf(v, w1.y, k[5]);
    }
}

extern "C" __global__ __launch_bounds__(NTHR, 1)
void ode_fused(const float* __restrict__ x0, const float* __restrict__ ts_g,
               const float* __restrict__ W1g, const float* __restrict__ b1g,
               const float* __restrict__ W2g, const float* __restrict__ b2g,
               const float* __restrict__ W3g, const float* __restrict__ b3g,
               float* __restrict__ out, int nt)
{
    __shared__ float sm[SMEM_FLOATS];
    const int tid = threadIdx.x;
    const int b   = blockIdx.x * NTHR + tid;

    // ---- stage weights (padded) + t_span into LDS ----
    for (int idx = tid; idx < D_IN * HP; idx += NTHR) {
        int r = idx / HP, c = idx - r * HP;
        sm[OFF_W1 + idx] = (c < H) ? W1g[r * H + c] : 0.0f;
    }
    for (int idx = tid; idx < HP; idx += NTHR)
        sm[OFF_B1 + idx] = (idx < H) ? b1g[idx] : 0.0f;
    for (int idx = tid; idx < H * HP; idx += NTHR) {
        int r = idx / HP, c = idx - r * HP;
        sm[OFF_W2 + idx] = (c < H) ? W2g[r * H + c] : 0.0f;
    }
    for (int idx = tid; idx < HP; idx += NTHR)
        sm[OFF_B2 + idx] = (idx < H) ? b2g[idx] : 0.0f;
    for (int idx = tid; idx < H * W3P; idx += NTHR) {
        int r = idx >> 3, c = idx & 7;
        sm[OFF_W3 + idx] = (c < D_IN) ? W3g[r * D_IN + c] : 0.0f;
    }
    for (int idx = tid; idx < W3P; idx += NTHR)
        sm[OFF_B3 + idx] = (idx < D_IN) ? b3g[idx] : 0.0f;
    for (int idx = tid; idx < nt && idx < 104; idx += NTHR)
        sm[OFF_TS + idx] = ts_g[idx];

    // ---- phase 1: y0 = mean over T (1200 contiguous floats per element) ----
    const float4* xrow = (const float4*)(x0 + (size_t)b * (T_LEN * D_IN));
    float acc[D_IN];
#pragma unroll
    for (int d = 0; d < D_IN; ++d) acc[d] = 0.0f;
#pragma unroll 4
    for (int c = 0; c < (T_LEN * D_IN) / 12; ++c) {
        float4 v0 = xrow[c * 3 + 0];
        float4 v1 = xrow[c * 3 + 1];
        float4 v2 = xrow[c * 3 + 2];
        acc[0] += v0.x + v1.z;
        acc[1] += v0.y + v1.w;
        acc[2] += v0.z + v2.x;
        acc[3] += v0.w + v2.y;
        acc[4] += v1.x + v2.z;
        acc[5] += v1.y + v2.w;
    }
    float y[D_IN];
#pragma unroll
    for (int d = 0; d < D_IN; ++d) y[d] = acc[d] * (1.0f / (float)T_LEN);

    __syncthreads();   // weights + ts visible; no further barriers needed
                       // (each thread touches only its own sH1 column)

    // ---- phase 2: RK4 over nt-1 steps ----
#pragma unroll 1
    for (int s = 0; s < nt - 1; ++s) {
        float t0 = sm[OFF_TS + s];
        float t1 = sm[OFF_TS + s + 1];
        float dt = t1 - t0;

        float acck[D_IN];
        float yt[D_IN];
#pragma unroll
        for (int d = 0; d < D_IN; ++d) { acck[d] = 0.0f; yt[d] = y[d]; }

#pragma unroll 1
        for (int st = 0; st < 4; ++st) {
            float k[D_IN];
            mlp_eval(sm, tid, yt, k);
            float w = (st == 1 || st == 2) ? 2.0f : 1.0f;  // k weights 1,2,2,1
            float a = (st == 2) ? 1.0f : 0.5f;             // y-offset coeff
#pragma unroll
            for (int d = 0; d < D_IN; ++d) {
                acck[d] = fmaf(w, k[d], acck[d]);
                yt[d]   = fmaf(a * dt, k[d], y[d]);
            }
        }
#pragma unroll
        for (int d = 0; d < D_IN; ++d) y[d] = fmaf(dt * (1.0f / 6.0f), acck[d], y[d]);
    }

    // ---- write y[-1] ----
    float* o = out + (size_t)b * D_IN;
#pragma unroll
    for (int d = 0; d < D_IN; ++d) o[d] = y[d];
}

extern "C" void kernel_launch(void* const* d_in, const int* in_sizes, int n_in,
                              void* d_out, int out_size, void* d_ws, size_t ws_size,
                              hipStream_t stream) {
    const float* x0 = (const float*)d_in[0];
    const float* ts = (const float*)d_in[1];
    const float* W1 = (const float*)d_in[2];
    const float* b1 = (const float*)d_in[3];
    const float* W2 = (const float*)d_in[4];
    const float* b2 = (const float*)d_in[5];
    const float* W3 = (const float*)d_in[6];
    const float* b3 = (const float*)d_in[7];
    float* out = (float*)d_out;

    int B  = in_sizes[0] / (T_LEN * D_IN);
    int nt = in_sizes[1];

    dim3 block(NTHR);
    dim3 grid(B / NTHR);  // B = 65536, exact multiple -- no tail
    hipLaunchKernelGGL(ode_fused, grid, block, 0, stream,
                       x0, ts, W1, b1, W2, b2, W3, b3, out, nt);
}

// Round 2
// 6201.043 us; speedup vs baseline: 1.3553x; 1.3553x over previous
//
#include <hip/hip_runtime.h>
#include <cstdint>

// ODEModel: y0 = mean_T(x0[B,200,6]); 101 RK4 steps of 6->50->50->6 ReLU MLP.
// One thread per batch element (lane = batch element). 1 wave/SIMD by grid.
//
// R3 theory (from R2 counters): R2 put weights in LDS -> wave-uniform
// ds_read_b128 is charged full per-lane bandwidth (64 x 16B = 1KiB per instr;
// LDS broadcast dedupes CONFLICTS, not BANDWIDTH) -> 956 DS ops/eval x 12cyc
// x 4 waves/CU = 46k cyc/eval = the measured 48k. LDS is hopeless for uniform
// data. R1's counters (92% VALU x 4.85ms = 13.2k VALU instr/eval vs 3.1k FMA)
// show per-lane SCALAR weight loads with ~3 VALU of 64-bit addressing each --
// but also prove same-address VMEM loads themselves are cheap (coalesced to 1
// request, broadcast return).
// R3: weights via per-lane float4 VMEM loads (L1-resident, 12.8KB) with
// base+imm13 addressing (zero VALU per load):
//  - W1/W3 walked LINEARLY as 75 aligned float4s, fully unrolled (static idx).
//  - W2 walked as row-PAIRS (100 floats = exactly 25 aligned float4s), rolled
//    loop over 25 pairs, manually double-buffered in registers (named A/B
//    buffers only -- no runtime-indexed arrays, rule #20).
//  - h1 needs dynamic (uniform-counter) indexing in layer 2 -> per-lane b32
//    LDS echo [j][tid] (conflict-free, 4B/lane: 100 LDS ops/eval, 250x less
//    LDS traffic than R2).
//  - biases folded as v_fma third operand (no h-init movs).
// Accumulation order identical to R1/R2 (i-major) -> absmax unchanged.

#define D_IN   6
#define H      50
#define T_LEN  200
#define NTHR   256
#define NPAIR  25

__device__ __forceinline__ float f4c(float4 v, int c) {
    return c == 0 ? v.x : c == 1 ? v.y : c == 2 ? v.z : v.w;
}

// ---- layer 2 helpers (all indices compile-time after unroll) ----
__device__ __forceinline__ void load_pair(float4 (&buf)[NPAIR], const float4* W2f4, int p,
                                          float& v0, float& v1, const float* echoT)
{
    const float4* w = W2f4 + p * NPAIR;
#pragma unroll
    for (int q = 0; q < NPAIR; ++q) buf[q] = w[q];
    v0 = echoT[(2 * p) * NTHR];        // relu(h1[2p])
    v1 = echoT[(2 * p + 1) * NTHR];    // relu(h1[2p+1])
}

__device__ __forceinline__ void fma_pair(const float4 (&buf)[NPAIR], float v0, float v1,
                                         float (&h2)[H])
{
    // pair p covers W2 rows i0=2p (elements 0..49) and i1=2p+1 (50..99).
    // i-major order preserved: all i0 terms (q=0..12.xy) before i1 terms.
#pragma unroll
    for (int q = 0; q < 12; ++q) {
        h2[4 * q + 0] = fmaf(v0, buf[q].x, h2[4 * q + 0]);
        h2[4 * q + 1] = fmaf(v0, buf[q].y, h2[4 * q + 1]);
        h2[4 * q + 2] = fmaf(v0, buf[q].z, h2[4 * q + 2]);
        h2[4 * q + 3] = fmaf(v0, buf[q].w, h2[4 * q + 3]);
    }
    h2[48] = fmaf(v0, buf[12].x, h2[48]);
    h2[49] = fmaf(v0, buf[12].y, h2[49]);
    h2[0]  = fmaf(v1, buf[12].z, h2[0]);
    h2[1]  = fmaf(v1, buf[12].w, h2[1]);
#pragma unroll
    for (int q = 13; q < NPAIR; ++q) {
        int jb = 4 * q - 50;
        h2[jb + 0] = fmaf(v1, buf[q].x, h2[jb + 0]);
        h2[jb + 1] = fmaf(v1, buf[q].y, h2[jb + 1]);
        h2[jb + 2] = fmaf(v1, buf[q].z, h2[jb + 2]);
        h2[jb + 3] = fmaf(v1, buf[q].w, h2[jb + 3]);
    }
}

extern "C" __global__ __launch_bounds__(NTHR, 1)
void ode_fused(const float* __restrict__ x0, const float* __restrict__ ts_g,
               const float* __restrict__ W1g, const float* __restrict__ b1g,
               const float* __restrict__ W2g, const float* __restrict__ b2g,
               const float* __restrict__ W3g, const float* __restrict__ b3g,
               float* __restrict__ out, int nt)
{
    __shared__ float echo[H * NTHR];   // 50 KB: relu(h1) echo, [j][tid]
    const int tid = threadIdx.x;
    const int b   = blockIdx.x * NTHR + tid;
    float* echoT  = echo + tid;

    const float4* W1f4 = (const float4*)W1g;   // 300 floats = 75 f4, aligned
    const float4* W2f4 = (const float4*)W2g;   // 2500 floats; pairs of rows = 25 f4
    const float4* W3f4 = (const float4*)W3g;   // 300 floats = 75 f4, aligned

    // ---- phase 1: y0 = mean over T of x0[b,:,:] (1200 contiguous floats) ----
    const float4* xrow = (const float4*)(x0 + (size_t)b * (T_LEN * D_IN));
    float acc[D_IN];
#pragma unroll
    for (int d = 0; d < D_IN; ++d) acc[d] = 0.0f;
#pragma unroll 4
    for (int c = 0; c < (T_LEN * D_IN) / 12; ++c) {
        float4 v0 = xrow[c * 3 + 0];
        float4 v1 = xrow[c * 3 + 1];
        float4 v2 = xrow[c * 3 + 2];
        acc[0] += v0.x + v1.z;
        acc[1] += v0.y + v1.w;
        acc[2] += v0.z + v2.x;
        acc[3] += v0.w + v2.y;
        acc[4] += v1.x + v2.z;
        acc[5] += v1.y + v2.w;
    }
    float y[D_IN];
#pragma unroll
    for (int d = 0; d < D_IN; ++d) y[d] = acc[d] * (1.0f / (float)T_LEN);

    // ---- phase 2: RK4 over nt-1 steps ----
#pragma unroll 1
    for (int s = 0; s < nt - 1; ++s) {
        float t0 = ts_g[s];
        float t1 = ts_g[s + 1];
        float dt = t1 - t0;

        float acck[D_IN];
        float yt[D_IN];
#pragma unroll
        for (int d = 0; d < D_IN; ++d) { acck[d] = 0.0f; yt[d] = y[d]; }

#pragma unroll 1
        for (int st = 0; st < 4; ++st) {
            // ================= MLP eval: yt -> k =================
            // ---- layer 1: 6 -> 50; W1 walked as 75 f4, bias as fma addend ----
            float4 B1[12];
#pragma unroll
            for (int q = 0; q < 12; ++q) B1[q] = ((const float4*)b1g)[q];
            float2 b1t = *(const float2*)(b1g + 48);

            float h1[H];
#pragma unroll
            for (int m = 0; m < 75; ++m) {
                float4 w = W1f4[m];
#pragma unroll
                for (int c = 0; c < 4; ++c) {
                    int e = 4 * m + c;          // linear element of W1
                    int i = e / H;              // input index (row)
                    int j = e - H * i;          // output index (col)
                    float bj  = (j < 48) ? f4c(B1[j >> 2], j & 3)
                                         : (j == 48 ? b1t.x : b1t.y);
                    float add = (e < H) ? bj : h1[j];   // first row seeds bias
                    h1[j] = fmaf(yt[i], f4c(w, c), add);
                }
            }

            // echo relu(h1) for dynamic indexing in layer 2 ([j][tid]: bank =
            // tid%32, 2 lanes/bank = conflict-free; 4B/lane -> cheap)
#pragma unroll
            for (int j = 0; j < H; ++j) echoT[j * NTHR] = fmaxf(h1[j], 0.0f);

            // ---- layer 2: 50 -> 50; 25 row-pairs, double-buffered ----
            float h2[H];
            {
                // pair 0 seeds h2 from bias b2
                float4 B2[12];
#pragma unroll
                for (int q = 0; q < 12; ++q) B2[q] = ((const float4*)b2g)[q];
                float2 b2t = *(const float2*)(b2g + 48);

                float4 P[NPAIR];
                float v0, v1;
                load_pair(P, W2f4, 0, v0, v1, echoT);
#pragma unroll
                for (int q = 0; q < 12; ++q) {
                    h2[4 * q + 0] = fmaf(v0, P[q].x, f4c(B2[q], 0));
                    h2[4 * q + 1] = fmaf(v0, P[q].y, f4c(B2[q], 1));
                    h2[4 * q + 2] = fmaf(v0, P[q].z, f4c(B2[q], 2));
                    h2[4 * q + 3] = fmaf(v0, P[q].w, f4c(B2[q], 3));
                }
                h2[48] = fmaf(v0, P[12].x, b2t.x);
                h2[49] = fmaf(v0, P[12].y, b2t.y);
                h2[0]  = fmaf(v1, P[12].z, h2[0]);
                h2[1]  = fmaf(v1, P[12].w, h2[1]);
#pragma unroll
                for (int q = 13; q < NPAIR; ++q) {
                    int jb = 4 * q - 50;
                    h2[jb + 0] = fmaf(v1, P[q].x, h2[jb + 0]);
                    h2[jb + 1] = fmaf(v1, P[q].y, h2[jb + 1]);
                    h2[jb + 2] = fmaf(v1, P[q].z, h2[jb + 2]);
                    h2[jb + 3] = fmaf(v1, P[q].w, h2[jb + 3]);
                }
            }
            {
                // pairs 1..24: software-pipelined (load next while FMA current)
                float4 A[NPAIR], Bb[NPAIR];
                float v0A, v1A, v0B, v1B;
                load_pair(A, W2f4, 1, v0A, v1A, echoT);
#pragma unroll 1
                for (int it = 0; it < 11; ++it) {
                    load_pair(Bb, W2f4, 2 * it + 2, v0B, v1B, echoT);
                    fma_pair(A, v0A, v1A, h2);               // pair 2it+1
                    load_pair(A, W2f4, 2 * it + 3, v0A, v1A, echoT);
                    fma_pair(Bb, v0B, v1B, h2);              // pair 2it+2
                }
                load_pair(Bb, W2f4, 24, v0B, v1B, echoT);
                fma_pair(A, v0A, v1A, h2);                   // pair 23
                fma_pair(Bb, v0B, v1B, h2);                  // pair 24
            }

            // ---- layer 3: 50 -> 6; relu at consumption; W3 as 75 f4 ----
            float h2r[H];
#pragma unroll
            for (int j = 0; j < H; ++j) h2r[j] = fmaxf(h2[j], 0.0f);

            float4 b3a = *(const float4*)b3g;
            float2 b3t = *(const float2*)(b3g + 4);

            float k[D_IN];
#pragma unroll
            for (int m = 0; m < 75; ++m) {
                float4 w = W3f4[m];
#pragma unroll
                for (int c = 0; c < 4; ++c) {
                    int e = 4 * m + c;          // linear element of W3
                    int i = e / D_IN;           // input index (row)
                    int d = e - D_IN * i;       // output index (col)
                    float bd  = (d < 4) ? f4c(b3a, d) : (d == 4 ? b3t.x : b3t.y);
                    float add = (e < D_IN) ? bd : k[d];
                    k[d] = fmaf(h2r[i], f4c(w, c), add);
                }
            }
            // ================= end MLP eval =================

            float w = (st == 1 || st == 2) ? 2.0f : 1.0f;  // k weights 1,2,2,1
            float a = (st == 2) ? 1.0f : 0.5f;             // y-offset coeff
#pragma unroll
            for (int d = 0; d < D_IN; ++d) {
                acck[d] = fmaf(w, k[d], acck[d]);
                yt[d]   = fmaf(a * dt, k[d], y[d]);
            }
        }
#pragma unroll
        for (int d = 0; d < D_IN; ++d) y[d] = fmaf(dt * (1.0f / 6.0f), acck[d], y[d]);
    }

    // ---- write y[-1] ----
    float* o = out + (size_t)b * D_IN;
#pragma unroll
    for (int d = 0; d < D_IN; ++d) o[d] = y[d];
}

extern "C" void kernel_launch(void* const* d_in, const int* in_sizes, int n_in,
                              void* d_out, int out_size, void* d_ws, size_t ws_size,
                              hipStream_t stream) {
    const float* x0 = (const float*)d_in[0];
    const float* ts = (const float*)d_in[1];
    const float* W1 = (const float*)d_in[2];
    const float* b1 = (const float*)d_in[3];
    const float* W2 = (const float*)d_in[4];
    const float* b2 = (const float*)d_in[5];
    const float* W3 = (const float*)d_in[6];
    const float* b3 = (const float*)d_in[7];
    float* out = (float*)d_out;

    int B  = in_sizes[0] / (T_LEN * D_IN);
    int nt = in_sizes[1];

    dim3 block(NTHR);
    dim3 grid(B / NTHR);  // B = 65536, exact multiple -- no tail
    hipLaunchKernelGGL(ode_fused, grid, block, 0, stream,
                       x0, ts, W1, b1, W2, b2, W3, b3, out, nt);
}